// Round 1
// baseline (1889.143 us; speedup 1.0000x reference)
//
#include <hip/hip_runtime.h>

// GRU: T=512, B=256, I=H=256, fp32 in/out.
// Stage A (parallel): Gx = x @ Wx_cat^T + b for all T,B, bf16 in d_ws, tiled
//   layout idx = ((j*16 + b/16)*512 + t)*16 + (b%16), j in [0,768).
// Stage B (recurrent): 16 WGs x 512 thr; 16 batch rows per WG (batch rows are
//   independent -> no inter-WG communication); h-weights (3x256x256) held in
//   registers as bf16 MFMA B-fragments for the whole 512-step loop.

typedef float f32x4 __attribute__((ext_vector_type(4)));
typedef short bf16x8 __attribute__((ext_vector_type(8)));

__device__ __forceinline__ unsigned short f2bf(float f) {
  union { float f; unsigned int u; } v; v.f = f;
  unsigned int u = v.u + 0x7fffu + ((v.u >> 16) & 1u);   // RNE
  return (unsigned short)(u >> 16);
}
__device__ __forceinline__ float bf2f(unsigned short s) {
  union { unsigned int u; float f; } v; v.u = ((unsigned int)s) << 16;
  return v.f;
}
__device__ __forceinline__ float sigmoid_f(float x) {
  return __builtin_amdgcn_rcpf(1.f + __expf(-x));
}
__device__ __forceinline__ float tanh_f(float x) {
  float e = __expf(2.f * x);
  return 1.f - 2.f * __builtin_amdgcn_rcpf(e + 1.f);
}

// ---------------- Stage A ----------------
// grid (2048, 12), block 256 (4 waves). Tile 64M x 64N, K=256 in 4 chunks.
__global__ __launch_bounds__(256) void gru_gx_kernel(
    const float* __restrict__ x,
    const float* __restrict__ Wz, const float* __restrict__ Wr, const float* __restrict__ Wc,
    const float* __restrict__ bz, const float* __restrict__ br, const float* __restrict__ bc,
    unsigned short* __restrict__ gx)
{
  __shared__ __align__(16) unsigned short As[64][72];  // [m][k] bf16, +8 pad
  __shared__ __align__(16) unsigned short Bs[64][72];  // [j][k] bf16

  const int tid  = threadIdx.x;
  const int lane = tid & 63;
  const int wid  = tid >> 6;       // 0..3
  const int l15  = lane & 15;
  const int lg   = lane >> 4;      // 0..3
  const int m0   = blockIdx.x * 64;      // m = t*256 + b
  const int by   = blockIdx.y;           // 0..11
  const int gate = by >> 2;
  const int jb   = (by & 3) * 64;
  const float* W    = (gate == 0) ? Wz : ((gate == 1) ? Wr : Wc);
  const float* bias = (gate == 0) ? bz : ((gate == 1) ? br : bc);

  f32x4 acc[4];
  #pragma unroll
  for (int n = 0; n < 4; ++n) acc[n] = (f32x4){0.f, 0.f, 0.f, 0.f};

  for (int k0 = 0; k0 < 256; k0 += 64) {
    #pragma unroll
    for (int i = 0; i < 4; ++i) {
      int idx = tid + i * 256;              // 0..1023
      int row = idx >> 4;                   // 0..63
      int kq  = (idx & 15) << 2;            // 0..60 step 4
      float4 va = *(const float4*)(x + (size_t)(m0 + row) * 256 + k0 + kq);
      ushort4 ua; ua.x = f2bf(va.x); ua.y = f2bf(va.y); ua.z = f2bf(va.z); ua.w = f2bf(va.w);
      *(ushort4*)&As[row][kq] = ua;
      float4 vb = *(const float4*)(W + (size_t)(jb + row) * 512 + 256 + k0 + kq);
      ushort4 ub; ub.x = f2bf(vb.x); ub.y = f2bf(vb.y); ub.z = f2bf(vb.z); ub.w = f2bf(vb.w);
      *(ushort4*)&Bs[row][kq] = ub;
    }
    __syncthreads();
    #pragma unroll
    for (int ks = 0; ks < 64; ks += 32) {
      bf16x8 af = *(const bf16x8*)&As[wid * 16 + l15][ks + lg * 8];
      #pragma unroll
      for (int n = 0; n < 4; ++n) {
        bf16x8 bf = *(const bf16x8*)&Bs[n * 16 + l15][ks + lg * 8];
        acc[n] = __builtin_amdgcn_mfma_f32_16x16x32_bf16(af, bf, acc[n], 0, 0, 0);
      }
    }
    __syncthreads();
  }

  // bias + bf16; transpose through LDS (reuse As as Ts[col][mrow])
  #pragma unroll
  for (int n = 0; n < 4; ++n) {
    float bv = bias[jb + n * 16 + l15];
    #pragma unroll
    for (int r = 0; r < 4; ++r) {
      As[n * 16 + l15][wid * 16 + lg * 4 + r] = f2bf(acc[n][r] + bv);
    }
  }
  __syncthreads();

  const int tt    = m0 >> 8;       // t (tile spans a single t since 64 | 256)
  const int b0    = m0 & 255;      // batch base, 64-aligned
  const int jbase = by * 64;       // global output col
  #pragma unroll
  for (int i = 0; i < 2; ++i) {
    int idx = tid + i * 256;       // 0..511
    int col = idx >> 3;            // 0..63
    int rq  = (idx & 7) << 3;      // mrow start (8 elems, stays in one 16-blk half)
    int jg  = jbase + col;
    int b   = b0 + rq;
    size_t off = (((size_t)jg * 16 + (size_t)(b >> 4)) * 512 + (size_t)tt) * 16 + (size_t)(b & 15);
    *(uint4*)(gx + off) = *(const uint4*)&As[col][rq];
  }
}

// ---------------- Stage B ----------------
// grid 16, block 512 (8 waves). WG b owns batch rows [16b, 16b+16).
// Phase 1: waves 0-3 -> z cols (0..255), waves 4-7 -> r cols (256..511).
// Phase 2: all 8 waves -> cand, 32 cols each.
__global__ __launch_bounds__(512, 2) void gru_rec_kernel(
    const unsigned short* __restrict__ gx,
    const float* __restrict__ h0,
    const float* __restrict__ Wz, const float* __restrict__ Wr, const float* __restrict__ Wc,
    float* __restrict__ out)
{
  __shared__ float h_s[16][260];                       // fp32 h state (+4 pad)
  __shared__ float zt_s[16][260];                      // fp32 z gate
  __shared__ __align__(16) unsigned short hA[16][264]; // bf16 h, A-frag layout (+8 pad)
  __shared__ __align__(16) unsigned short rhA[16][264];// bf16 r*h

  const int tid   = threadIdx.x;
  const int lane  = tid & 63;
  const int wid   = tid >> 6;       // 0..7
  const int l15   = lane & 15;
  const int lg    = lane >> 4;      // 0..3
  const int brow0 = blockIdx.x * 16;

  // ---- persistent weights: bf16 B-fragments in registers ----
  bf16x8 w1[4][8];   // phase-1: 64 cols (z or r), K=256  -> 128 VGPRs
  {
    const float* W  = (wid < 4) ? Wz : Wr;
    const int    cb = (wid & 3) * 64;
    #pragma unroll
    for (int n = 0; n < 4; ++n) {
      const int j = cb + n * 16 + l15;
      #pragma unroll
      for (int kk = 0; kk < 8; ++kk) {
        const int k = kk * 32 + lg * 8;
        const float* p = W + (size_t)j * 512 + k;      // h-part: cols [0,256)
        float4 a = *(const float4*)p;
        float4 b = *(const float4*)(p + 4);
        bf16x8 f;
        f[0] = (short)f2bf(a.x); f[1] = (short)f2bf(a.y);
        f[2] = (short)f2bf(a.z); f[3] = (short)f2bf(a.w);
        f[4] = (short)f2bf(b.x); f[5] = (short)f2bf(b.y);
        f[6] = (short)f2bf(b.z); f[7] = (short)f2bf(b.w);
        w1[n][kk] = f;
      }
    }
  }
  bf16x8 w2[2][8];   // phase-2: 32 cand cols, K=256 -> 64 VGPRs
  {
    const int cb = wid * 32;
    #pragma unroll
    for (int n = 0; n < 2; ++n) {
      const int j = cb + n * 16 + l15;
      #pragma unroll
      for (int kk = 0; kk < 8; ++kk) {
        const int k = kk * 32 + lg * 8;
        const float* p = Wc + (size_t)j * 512 + k;
        float4 a = *(const float4*)p;
        float4 b = *(const float4*)(p + 4);
        bf16x8 f;
        f[0] = (short)f2bf(a.x); f[1] = (short)f2bf(a.y);
        f[2] = (short)f2bf(a.z); f[3] = (short)f2bf(a.w);
        f[4] = (short)f2bf(b.x); f[5] = (short)f2bf(b.y);
        f[6] = (short)f2bf(b.z); f[7] = (short)f2bf(b.w);
        w2[n][kk] = f;
      }
    }
  }

  // ---- init h ----
  for (int idx = tid; idx < 16 * 256; idx += 512) {
    int r = idx >> 8, c = idx & 255;
    float v = h0[(size_t)(brow0 + r) * 256 + c];
    h_s[r][c] = v;
    hA[r][c]  = f2bf(v);
  }
  __syncthreads();

  const size_t blkoff = (size_t)blockIdx.x * 8192;   // blk*512*16 in gx layout

  for (int t = 0; t < 512; ++t) {
    // ---------- phase 1: z,r ----------
    uint2 gx1[4];
    const int jb1 = wid * 64;                        // global col in [0,512)
    #pragma unroll
    for (int n = 0; n < 4; ++n) {
      const unsigned short* p = gx + (size_t)(jb1 + n * 16 + l15) * 131072
                                   + blkoff + (size_t)t * 16 + lg * 4;
      gx1[n] = *(const uint2*)p;                     // 4 bf16: rows lg*4..lg*4+3
    }
    f32x4 acc[4];
    #pragma unroll
    for (int n = 0; n < 4; ++n) acc[n] = (f32x4){0.f, 0.f, 0.f, 0.f};
    #pragma unroll
    for (int kk = 0; kk < 8; ++kk) {
      bf16x8 af = *(const bf16x8*)&hA[l15][kk * 32 + lg * 8];
      #pragma unroll
      for (int n = 0; n < 4; ++n)
        acc[n] = __builtin_amdgcn_mfma_f32_16x16x32_bf16(af, w1[n][kk], acc[n], 0, 0, 0);
    }
    if (wid < 4) {         // z gate
      #pragma unroll
      for (int n = 0; n < 4; ++n) {
        const int col = jb1 + n * 16 + l15;
        #pragma unroll
        for (int r = 0; r < 4; ++r) {
          float pre = acc[n][r] + bf2f(((const unsigned short*)&gx1[n])[r]);
          zt_s[lg * 4 + r][col] = sigmoid_f(pre);
        }
      }
    } else {               // r gate -> r*h as bf16 A-frags
      #pragma unroll
      for (int n = 0; n < 4; ++n) {
        const int hc = (jb1 - 256) + n * 16 + l15;
        #pragma unroll
        for (int r = 0; r < 4; ++r) {
          const int row = lg * 4 + r;
          float pre = acc[n][r] + bf2f(((const unsigned short*)&gx1[n])[r]);
          float rv  = sigmoid_f(pre);
          rhA[row][hc] = f2bf(rv * h_s[row][hc]);
        }
      }
    }
    __syncthreads();

    // ---------- phase 2: cand + h update ----------
    uint2 gx2[2];
    const int jb2 = 512 + wid * 32;
    #pragma unroll
    for (int n = 0; n < 2; ++n) {
      const unsigned short* p = gx + (size_t)(jb2 + n * 16 + l15) * 131072
                                   + blkoff + (size_t)t * 16 + lg * 4;
      gx2[n] = *(const uint2*)p;
    }
    f32x4 acc2[2];
    #pragma unroll
    for (int n = 0; n < 2; ++n) acc2[n] = (f32x4){0.f, 0.f, 0.f, 0.f};
    #pragma unroll
    for (int kk = 0; kk < 8; ++kk) {
      bf16x8 af = *(const bf16x8*)&rhA[l15][kk * 32 + lg * 8];
      #pragma unroll
      for (int n = 0; n < 2; ++n)
        acc2[n] = __builtin_amdgcn_mfma_f32_16x16x32_bf16(af, w2[n][kk], acc2[n], 0, 0, 0);
    }
    #pragma unroll
    for (int n = 0; n < 2; ++n) {
      const int col = wid * 32 + n * 16 + l15;
      #pragma unroll
      for (int r = 0; r < 4; ++r) {
        const int row = lg * 4 + r;
        float pre = acc2[n][r] + bf2f(((const unsigned short*)&gx2[n])[r]);
        float th  = tanh_f(pre);
        float zv  = zt_s[row][col];
        float hp  = h_s[row][col];
        float ht  = (1.f - zv) * hp + zv * th;
        out[(size_t)t * 65536 + (size_t)(brow0 + row) * 256 + col] = ht;
        if (t == 511)
          out[(size_t)33554432 + (size_t)(brow0 + row) * 256 + col] = ht;
        h_s[row][col] = ht;
        hA[row][col]  = f2bf(ht);
      }
    }
    __syncthreads();
  }
}

extern "C" void kernel_launch(void* const* d_in, const int* in_sizes, int n_in,
                              void* d_out, int out_size, void* d_ws, size_t ws_size,
                              hipStream_t stream) {
  const float* x  = (const float*)d_in[0];
  const float* h0 = (const float*)d_in[1];
  const float* Wz = (const float*)d_in[2];
  const float* bz = (const float*)d_in[3];
  const float* Wr = (const float*)d_in[4];
  const float* br = (const float*)d_in[5];
  const float* Wc = (const float*)d_in[6];
  const float* bc = (const float*)d_in[7];
  float* out = (float*)d_out;
  unsigned short* gxbuf = (unsigned short*)d_ws;   // needs 768*131072*2 = 201.3 MB

  dim3 gridA(2048, 12);
  gru_gx_kernel<<<gridA, 256, 0, stream>>>(x, Wz, Wr, Wc, bz, br, bc, gxbuf);
  gru_rec_kernel<<<16, 512, 0, stream>>>(gxbuf, h0, Wz, Wr, Wc, out);
}

// Round 2
// 1807.060 us; speedup vs baseline: 1.0454x; 1.0454x over previous
//
#include <hip/hip_runtime.h>

// GRU: T=512, B=256, I=H=256, fp32 in/out.
// Stage A (parallel): Gx = x @ Wx_cat^T + b for all T,B, bf16 in d_ws,
//   t-major tiled layout: idx = ((t*16 + b/16)*768 + j)*16 + (b%16).
//   => per (t, batch-group) slice is 768*16*2B = 24KB contiguous.
// Stage B (recurrent): 16 WGs x 512 thr; 16 batch rows per WG; h-weights
//   (3x256x256) in registers as bf16 MFMA B-fragments; gx streamed via
//   global_load_lds into a 2x24KB LDS double buffer, prefetched 1 step ahead.

typedef float f32x4 __attribute__((ext_vector_type(4)));
typedef short bf16x8 __attribute__((ext_vector_type(8)));

__device__ __forceinline__ unsigned short f2bf(float f) {
  union { float f; unsigned int u; } v; v.f = f;
  unsigned int u = v.u + 0x7fffu + ((v.u >> 16) & 1u);   // RNE
  return (unsigned short)(u >> 16);
}
__device__ __forceinline__ float bf2f(unsigned short s) {
  union { unsigned int u; float f; } v; v.u = ((unsigned int)s) << 16;
  return v.f;
}
__device__ __forceinline__ float sigmoid_f(float x) {
  return __builtin_amdgcn_rcpf(1.f + __expf(-x));
}
__device__ __forceinline__ float tanh_f(float x) {
  float e = __expf(2.f * x);
  return 1.f - 2.f * __builtin_amdgcn_rcpf(e + 1.f);
}
__device__ __forceinline__ void gld_lds16(const unsigned short* g, unsigned short* l) {
  __builtin_amdgcn_global_load_lds(
      (const __attribute__((address_space(1))) unsigned int*)g,
      (__attribute__((address_space(3))) unsigned int*)l, 16, 0, 0);
}

// ---------------- Stage A ----------------
// grid (2048, 12), block 256 (4 waves). Tile 64M x 64N, K=256 in 4 chunks.
__global__ __launch_bounds__(256) void gru_gx_kernel(
    const float* __restrict__ x,
    const float* __restrict__ Wz, const float* __restrict__ Wr, const float* __restrict__ Wc,
    const float* __restrict__ bz, const float* __restrict__ br, const float* __restrict__ bc,
    unsigned short* __restrict__ gx)
{
  __shared__ __align__(16) unsigned short As[64][72];  // [m][k] bf16, +8 pad
  __shared__ __align__(16) unsigned short Bs[64][72];  // [j][k] bf16

  const int tid  = threadIdx.x;
  const int lane = tid & 63;
  const int wid  = tid >> 6;       // 0..3
  const int l15  = lane & 15;
  const int lg   = lane >> 4;      // 0..3
  const int m0   = blockIdx.x * 64;      // m = t*256 + b
  const int by   = blockIdx.y;           // 0..11
  const int gate = by >> 2;
  const int jb   = (by & 3) * 64;
  const float* W    = (gate == 0) ? Wz : ((gate == 1) ? Wr : Wc);
  const float* bias = (gate == 0) ? bz : ((gate == 1) ? br : bc);

  f32x4 acc[4];
  #pragma unroll
  for (int n = 0; n < 4; ++n) acc[n] = (f32x4){0.f, 0.f, 0.f, 0.f};

  for (int k0 = 0; k0 < 256; k0 += 64) {
    #pragma unroll
    for (int i = 0; i < 4; ++i) {
      int idx = tid + i * 256;              // 0..1023
      int row = idx >> 4;                   // 0..63
      int kq  = (idx & 15) << 2;            // 0..60 step 4
      float4 va = *(const float4*)(x + (size_t)(m0 + row) * 256 + k0 + kq);
      ushort4 ua; ua.x = f2bf(va.x); ua.y = f2bf(va.y); ua.z = f2bf(va.z); ua.w = f2bf(va.w);
      *(ushort4*)&As[row][kq] = ua;
      float4 vb = *(const float4*)(W + (size_t)(jb + row) * 512 + 256 + k0 + kq);
      ushort4 ub; ub.x = f2bf(vb.x); ub.y = f2bf(vb.y); ub.z = f2bf(vb.z); ub.w = f2bf(vb.w);
      *(ushort4*)&Bs[row][kq] = ub;
    }
    __syncthreads();
    #pragma unroll
    for (int ks = 0; ks < 64; ks += 32) {
      bf16x8 af = *(const bf16x8*)&As[wid * 16 + l15][ks + lg * 8];
      #pragma unroll
      for (int n = 0; n < 4; ++n) {
        bf16x8 bf = *(const bf16x8*)&Bs[n * 16 + l15][ks + lg * 8];
        acc[n] = __builtin_amdgcn_mfma_f32_16x16x32_bf16(af, bf, acc[n], 0, 0, 0);
      }
    }
    __syncthreads();
  }

  // bias + bf16; transpose through LDS (reuse As as Ts[col][mrow])
  #pragma unroll
  for (int n = 0; n < 4; ++n) {
    float bv = bias[jb + n * 16 + l15];
    #pragma unroll
    for (int r = 0; r < 4; ++r) {
      As[n * 16 + l15][wid * 16 + lg * 4 + r] = f2bf(acc[n][r] + bv);
    }
  }
  __syncthreads();

  const int tt    = m0 >> 8;       // t (tile spans a single t since 64 | 256)
  const int b0    = m0 & 255;      // batch base, 64-aligned
  const int jbase = by * 64;       // global output col
  #pragma unroll
  for (int i = 0; i < 2; ++i) {
    int idx = tid + i * 256;       // 0..511
    int col = idx >> 3;            // 0..63
    int rq  = (idx & 7) << 3;      // mrow start (8 elems, stays in one 16-blk half)
    int jg  = jbase + col;
    int b   = b0 + rq;
    size_t off = (((size_t)tt * 16 + (size_t)(b >> 4)) * 768 + (size_t)jg) * 16 + (size_t)(b & 15);
    *(uint4*)(gx + off) = *(const uint4*)&As[col][rq];
  }
}

// ---------------- Stage B ----------------
// grid 16, block 512 (8 waves). WG b owns batch rows [16b, 16b+16).
// Phase 1: waves 0-3 -> z cols (0..255), waves 4-7 -> r cols (256..511).
// Phase 2: all 8 waves -> cand, 32 cols each.
__global__ __launch_bounds__(512, 2) void gru_rec_kernel(
    const unsigned short* __restrict__ gx,
    const float* __restrict__ h0,
    const float* __restrict__ Wz, const float* __restrict__ Wr, const float* __restrict__ Wc,
    float* __restrict__ out)
{
  __shared__ float h_s[16][260];                       // fp32 h state (+4 pad)
  __shared__ float zt_s[16][260];                      // fp32 z gate
  __shared__ __align__(16) unsigned short hA[16][264]; // bf16 h, A-frag layout
  __shared__ __align__(16) unsigned short rhA[16][264];// bf16 r*h
  __shared__ __align__(16) unsigned short gxL[2][12288]; // 2 x 24KB gx stream dbuf

  const int tid   = threadIdx.x;
  const int lane  = tid & 63;
  const int wid   = tid >> 6;       // 0..7
  const int l15   = lane & 15;
  const int lg    = lane >> 4;      // 0..3
  const int wg    = blockIdx.x;
  const int brow0 = wg * 16;

  // ---- persistent weights: bf16 B-fragments in registers ----
  bf16x8 w1[4][8];   // phase-1: 64 cols (z or r), K=256  -> 128 regs
  {
    const float* W  = (wid < 4) ? Wz : Wr;
    const int    cb = (wid & 3) * 64;
    #pragma unroll
    for (int n = 0; n < 4; ++n) {
      const int j = cb + n * 16 + l15;
      #pragma unroll
      for (int kk = 0; kk < 8; ++kk) {
        const int k = kk * 32 + lg * 8;
        const float* p = W + (size_t)j * 512 + k;      // h-part: cols [0,256)
        float4 a = *(const float4*)p;
        float4 b = *(const float4*)(p + 4);
        bf16x8 f;
        f[0] = (short)f2bf(a.x); f[1] = (short)f2bf(a.y);
        f[2] = (short)f2bf(a.z); f[3] = (short)f2bf(a.w);
        f[4] = (short)f2bf(b.x); f[5] = (short)f2bf(b.y);
        f[6] = (short)f2bf(b.z); f[7] = (short)f2bf(b.w);
        w1[n][kk] = f;
      }
    }
  }
  bf16x8 w2[2][8];   // phase-2: 32 cand cols, K=256 -> 64 regs
  {
    const int cb = wid * 32;
    #pragma unroll
    for (int n = 0; n < 2; ++n) {
      const int j = cb + n * 16 + l15;
      #pragma unroll
      for (int kk = 0; kk < 8; ++kk) {
        const int k = kk * 32 + lg * 8;
        const float* p = Wc + (size_t)j * 512 + k;
        float4 a = *(const float4*)p;
        float4 b = *(const float4*)(p + 4);
        bf16x8 f;
        f[0] = (short)f2bf(a.x); f[1] = (short)f2bf(a.y);
        f[2] = (short)f2bf(a.z); f[3] = (short)f2bf(a.w);
        f[4] = (short)f2bf(b.x); f[5] = (short)f2bf(b.y);
        f[6] = (short)f2bf(b.z); f[7] = (short)f2bf(b.w);
        w2[n][kk] = f;
      }
    }
  }

  // ---- init h + prefetch step 0 ----
  for (int idx = tid; idx < 16 * 256; idx += 512) {
    int r = idx >> 8, c = idx & 255;
    float v = h0[(size_t)(brow0 + r) * 256 + c];
    h_s[r][c] = v;
    hA[r][c]  = f2bf(v);
  }
  {
    const unsigned short* src = gx + ((size_t)0 * 16 + wg) * 12288;
    #pragma unroll
    for (int i = 0; i < 3; ++i) {
      gld_lds16(src + (wid * 3 + i) * 512 + lane * 8, &gxL[0][(wid * 3 + i) * 512]);
    }
  }
  __syncthreads();   // drains vmcnt -> gxL[0] ready; hA visible

  int cur = 0;
  for (int t = 0; t < 512; ++t) {
    // ---- prefetch step t+1 into the other buffer ----
    {
      const int tn = (t < 511) ? (t + 1) : 511;
      const unsigned short* src = gx + ((size_t)tn * 16 + wg) * 12288;
      #pragma unroll
      for (int i = 0; i < 3; ++i) {
        gld_lds16(src + (wid * 3 + i) * 512 + lane * 8, &gxL[cur ^ 1][(wid * 3 + i) * 512]);
      }
    }

    // ---------- phase 1: z,r ----------
    const int jb1 = wid * 64;                        // global col in [0,512)
    f32x4 acc[4];
    #pragma unroll
    for (int n = 0; n < 4; ++n) acc[n] = (f32x4){0.f, 0.f, 0.f, 0.f};
    #pragma unroll
    for (int kk = 0; kk < 8; ++kk) {
      bf16x8 af = *(const bf16x8*)&hA[l15][kk * 32 + lg * 8];
      #pragma unroll
      for (int n = 0; n < 4; ++n)
        acc[n] = __builtin_amdgcn_mfma_f32_16x16x32_bf16(af, w1[n][kk], acc[n], 0, 0, 0);
    }
    if (wid < 4) {         // z gate
      #pragma unroll
      for (int n = 0; n < 4; ++n) {
        const int col = jb1 + n * 16 + l15;
        uint2 gv = *(const uint2*)&gxL[cur][col * 16 + lg * 4];
        #pragma unroll
        for (int r = 0; r < 4; ++r) {
          float pre = acc[n][r] + bf2f(((const unsigned short*)&gv)[r]);
          zt_s[lg * 4 + r][col] = sigmoid_f(pre);
        }
      }
    } else {               // r gate -> r*h as bf16 A-frags
      #pragma unroll
      for (int n = 0; n < 4; ++n) {
        const int col = jb1 + n * 16 + l15;          // 256..511
        const int hc  = col - 256;
        uint2 gv = *(const uint2*)&gxL[cur][col * 16 + lg * 4];
        #pragma unroll
        for (int r = 0; r < 4; ++r) {
          const int row = lg * 4 + r;
          float pre = acc[n][r] + bf2f(((const unsigned short*)&gv)[r]);
          float rv  = sigmoid_f(pre);
          rhA[row][hc] = f2bf(rv * h_s[row][hc]);
        }
      }
    }
    __syncthreads();

    // ---------- phase 2: cand + h update ----------
    f32x4 acc2[2];
    #pragma unroll
    for (int n = 0; n < 2; ++n) acc2[n] = (f32x4){0.f, 0.f, 0.f, 0.f};
    #pragma unroll
    for (int kk = 0; kk < 8; ++kk) {
      bf16x8 af = *(const bf16x8*)&rhA[l15][kk * 32 + lg * 8];
      #pragma unroll
      for (int n = 0; n < 2; ++n)
        acc2[n] = __builtin_amdgcn_mfma_f32_16x16x32_bf16(af, w2[n][kk], acc2[n], 0, 0, 0);
    }
    #pragma unroll
    for (int n = 0; n < 2; ++n) {
      const int col = wid * 32 + n * 16 + l15;
      uint2 gv = *(const uint2*)&gxL[cur][(512 + col) * 16 + lg * 4];
      #pragma unroll
      for (int r = 0; r < 4; ++r) {
        const int row = lg * 4 + r;
        float pre = acc2[n][r] + bf2f(((const unsigned short*)&gv)[r]);
        float th  = tanh_f(pre);
        float zv  = zt_s[row][col];
        float hp  = h_s[row][col];
        float ht  = (1.f - zv) * hp + zv * th;
        out[(size_t)t * 65536 + (size_t)(brow0 + row) * 256 + col] = ht;
        if (t == 511)
          out[(size_t)33554432 + (size_t)(brow0 + row) * 256 + col] = ht;
        h_s[row][col] = ht;
        hA[row][col]  = f2bf(ht);
      }
    }
    __syncthreads();
    cur ^= 1;
  }
}

extern "C" void kernel_launch(void* const* d_in, const int* in_sizes, int n_in,
                              void* d_out, int out_size, void* d_ws, size_t ws_size,
                              hipStream_t stream) {
  const float* x  = (const float*)d_in[0];
  const float* h0 = (const float*)d_in[1];
  const float* Wz = (const float*)d_in[2];
  const float* bz = (const float*)d_in[3];
  const float* Wr = (const float*)d_in[4];
  const float* br = (const float*)d_in[5];
  const float* Wc = (const float*)d_in[6];
  const float* bc = (const float*)d_in[7];
  float* out = (float*)d_out;
  unsigned short* gxbuf = (unsigned short*)d_ws;   // 768*131072*2 = 201.3 MB

  dim3 gridA(2048, 12);
  gru_gx_kernel<<<gridA, 256, 0, stream>>>(x, Wz, Wr, Wc, bz, br, bc, gxbuf);
  gru_rec_kernel<<<16, 512, 0, stream>>>(gxbuf, h0, Wz, Wr, Wc, out);
}

// Round 3
// 1806.985 us; speedup vs baseline: 1.0455x; 1.0000x over previous
//
#include <hip/hip_runtime.h>

// GRU: T=512, B=256, I=H=256, fp32 in/out.
// Stage A (parallel): Gx = x @ Wx_cat^T + b for all T,B, bf16 in d_ws,
//   t-major tiled layout: idx = ((t*16 + b/16)*768 + j)*16 + (b%16).
// Stage B (recurrent): 16 WGs x 512 thr; 16 batch rows per WG; h-weights
//   (3x256x256) in registers as bf16 MFMA B-fragments; gx streamed via
//   global_load_lds into a 2x24KB LDS double buffer, prefetched 1 step ahead.
// NOTE: launch_bounds 2nd arg acts as min-BLOCKS/CU in hipcc: (512,2) capped
//   VGPRs at 128 and spilled the 192-reg weight set -> 7300 cy/step scratch
//   reload. (512,1) -> 256-reg cap, weights stay resident.

typedef float f32x4 __attribute__((ext_vector_type(4)));
typedef short bf16x8 __attribute__((ext_vector_type(8)));

__device__ __forceinline__ unsigned short f2bf(float f) {
  union { float f; unsigned int u; } v; v.f = f;
  unsigned int u = v.u + 0x7fffu + ((v.u >> 16) & 1u);   // RNE
  return (unsigned short)(u >> 16);
}
__device__ __forceinline__ float bf2f(unsigned short s) {
  union { unsigned int u; float f; } v; v.u = ((unsigned int)s) << 16;
  return v.f;
}
__device__ __forceinline__ float sigmoid_f(float x) {
  return __builtin_amdgcn_rcpf(1.f + __expf(-x));
}
__device__ __forceinline__ float tanh_f(float x) {
  float e = __expf(2.f * x);
  return 1.f - 2.f * __builtin_amdgcn_rcpf(e + 1.f);
}
__device__ __forceinline__ void gld_lds16(const unsigned short* g, unsigned short* l) {
  __builtin_amdgcn_global_load_lds(
      (const __attribute__((address_space(1))) unsigned int*)g,
      (__attribute__((address_space(3))) unsigned int*)l, 16, 0, 0);
}

// ---------------- Stage A ----------------
// grid (2048, 12), block 256 (4 waves). Tile 64M x 64N, K=256 in 4 chunks.
__global__ __launch_bounds__(256) void gru_gx_kernel(
    const float* __restrict__ x,
    const float* __restrict__ Wz, const float* __restrict__ Wr, const float* __restrict__ Wc,
    const float* __restrict__ bz, const float* __restrict__ br, const float* __restrict__ bc,
    unsigned short* __restrict__ gx)
{
  __shared__ __align__(16) unsigned short As[64][72];  // [m][k] bf16, +8 pad
  __shared__ __align__(16) unsigned short Bs[64][72];  // [j][k] bf16

  const int tid  = threadIdx.x;
  const int lane = tid & 63;
  const int wid  = tid >> 6;       // 0..3
  const int l15  = lane & 15;
  const int lg   = lane >> 4;      // 0..3
  const int m0   = blockIdx.x * 64;      // m = t*256 + b
  const int by   = blockIdx.y;           // 0..11
  const int gate = by >> 2;
  const int jb   = (by & 3) * 64;
  const float* W    = (gate == 0) ? Wz : ((gate == 1) ? Wr : Wc);
  const float* bias = (gate == 0) ? bz : ((gate == 1) ? br : bc);

  f32x4 acc[4];
  #pragma unroll
  for (int n = 0; n < 4; ++n) acc[n] = (f32x4){0.f, 0.f, 0.f, 0.f};

  for (int k0 = 0; k0 < 256; k0 += 64) {
    #pragma unroll
    for (int i = 0; i < 4; ++i) {
      int idx = tid + i * 256;              // 0..1023
      int row = idx >> 4;                   // 0..63
      int kq  = (idx & 15) << 2;            // 0..60 step 4
      float4 va = *(const float4*)(x + (size_t)(m0 + row) * 256 + k0 + kq);
      ushort4 ua; ua.x = f2bf(va.x); ua.y = f2bf(va.y); ua.z = f2bf(va.z); ua.w = f2bf(va.w);
      *(ushort4*)&As[row][kq] = ua;
      float4 vb = *(const float4*)(W + (size_t)(jb + row) * 512 + 256 + k0 + kq);
      ushort4 ub; ub.x = f2bf(vb.x); ub.y = f2bf(vb.y); ub.z = f2bf(vb.z); ub.w = f2bf(vb.w);
      *(ushort4*)&Bs[row][kq] = ub;
    }
    __syncthreads();
    #pragma unroll
    for (int ks = 0; ks < 64; ks += 32) {
      bf16x8 af = *(const bf16x8*)&As[wid * 16 + l15][ks + lg * 8];
      #pragma unroll
      for (int n = 0; n < 4; ++n) {
        bf16x8 bf = *(const bf16x8*)&Bs[n * 16 + l15][ks + lg * 8];
        acc[n] = __builtin_amdgcn_mfma_f32_16x16x32_bf16(af, bf, acc[n], 0, 0, 0);
      }
    }
    __syncthreads();
  }

  // bias + bf16; transpose through LDS (reuse As as Ts[col][mrow])
  #pragma unroll
  for (int n = 0; n < 4; ++n) {
    float bv = bias[jb + n * 16 + l15];
    #pragma unroll
    for (int r = 0; r < 4; ++r) {
      As[n * 16 + l15][wid * 16 + lg * 4 + r] = f2bf(acc[n][r] + bv);
    }
  }
  __syncthreads();

  const int tt    = m0 >> 8;       // t (tile spans a single t since 64 | 256)
  const int b0    = m0 & 255;      // batch base, 64-aligned
  const int jbase = by * 64;       // global output col
  #pragma unroll
  for (int i = 0; i < 2; ++i) {
    int idx = tid + i * 256;       // 0..511
    int col = idx >> 3;            // 0..63
    int rq  = (idx & 7) << 3;      // mrow start (8 elems, stays in one 16-blk half)
    int jg  = jbase + col;
    int b   = b0 + rq;
    size_t off = (((size_t)tt * 16 + (size_t)(b >> 4)) * 768 + (size_t)jg) * 16 + (size_t)(b & 15);
    *(uint4*)(gx + off) = *(const uint4*)&As[col][rq];
  }
}

// ---------------- Stage B ----------------
// grid 16, block 512 (8 waves). WG b owns batch rows [16b, 16b+16).
// Phase 1: waves 0-3 -> z cols (0..255), waves 4-7 -> r cols (256..511).
// Phase 2: all 8 waves -> cand, 32 cols each.
__global__ __launch_bounds__(512, 1) void gru_rec_kernel(
    const unsigned short* __restrict__ gx,
    const float* __restrict__ h0,
    const float* __restrict__ Wz, const float* __restrict__ Wr, const float* __restrict__ Wc,
    float* __restrict__ out)
{
  __shared__ float h_s[16][260];                       // fp32 h state (+4 pad)
  __shared__ float zt_s[16][260];                      // fp32 z gate
  __shared__ __align__(16) unsigned short hA[16][264]; // bf16 h, A-frag layout
  __shared__ __align__(16) unsigned short rhA[16][264];// bf16 r*h
  __shared__ __align__(16) unsigned short gxL[2][12288]; // 2 x 24KB gx stream dbuf

  const int tid   = threadIdx.x;
  const int lane  = tid & 63;
  const int wid   = tid >> 6;       // 0..7
  const int l15   = lane & 15;
  const int lg    = lane >> 4;      // 0..3
  const int wg    = blockIdx.x;
  const int brow0 = wg * 16;

  // ---- persistent weights: bf16 B-fragments in registers ----
  bf16x8 w1[4][8];   // phase-1: 64 cols (z or r), K=256  -> 128 regs
  {
    const float* W  = (wid < 4) ? Wz : Wr;
    const int    cb = (wid & 3) * 64;
    #pragma unroll
    for (int n = 0; n < 4; ++n) {
      const int j = cb + n * 16 + l15;
      #pragma unroll
      for (int kk = 0; kk < 8; ++kk) {
        const int k = kk * 32 + lg * 8;
        const float* p = W + (size_t)j * 512 + k;      // h-part: cols [0,256)
        float4 a = *(const float4*)p;
        float4 b = *(const float4*)(p + 4);
        bf16x8 f;
        f[0] = (short)f2bf(a.x); f[1] = (short)f2bf(a.y);
        f[2] = (short)f2bf(a.z); f[3] = (short)f2bf(a.w);
        f[4] = (short)f2bf(b.x); f[5] = (short)f2bf(b.y);
        f[6] = (short)f2bf(b.z); f[7] = (short)f2bf(b.w);
        w1[n][kk] = f;
      }
    }
  }
  bf16x8 w2[2][8];   // phase-2: 32 cand cols, K=256 -> 64 regs
  {
    const int cb = wid * 32;
    #pragma unroll
    for (int n = 0; n < 2; ++n) {
      const int j = cb + n * 16 + l15;
      #pragma unroll
      for (int kk = 0; kk < 8; ++kk) {
        const int k = kk * 32 + lg * 8;
        const float* p = Wc + (size_t)j * 512 + k;
        float4 a = *(const float4*)p;
        float4 b = *(const float4*)(p + 4);
        bf16x8 f;
        f[0] = (short)f2bf(a.x); f[1] = (short)f2bf(a.y);
        f[2] = (short)f2bf(a.z); f[3] = (short)f2bf(a.w);
        f[4] = (short)f2bf(b.x); f[5] = (short)f2bf(b.y);
        f[6] = (short)f2bf(b.z); f[7] = (short)f2bf(b.w);
        w2[n][kk] = f;
      }
    }
  }

  // ---- init h + prefetch step 0 ----
  for (int idx = tid; idx < 16 * 256; idx += 512) {
    int r = idx >> 8, c = idx & 255;
    float v = h0[(size_t)(brow0 + r) * 256 + c];
    h_s[r][c] = v;
    hA[r][c]  = f2bf(v);
  }
  {
    const unsigned short* src = gx + ((size_t)0 * 16 + wg) * 12288;
    #pragma unroll
    for (int i = 0; i < 3; ++i) {
      gld_lds16(src + (wid * 3 + i) * 512 + lane * 8, &gxL[0][(wid * 3 + i) * 512]);
    }
  }
  __syncthreads();   // drains vmcnt -> gxL[0] ready; hA visible

  int cur = 0;
  for (int t = 0; t < 512; ++t) {
    // ---- prefetch step t+1 into the other buffer ----
    {
      const int tn = (t < 511) ? (t + 1) : 511;
      const unsigned short* src = gx + ((size_t)tn * 16 + wg) * 12288;
      #pragma unroll
      for (int i = 0; i < 3; ++i) {
        gld_lds16(src + (wid * 3 + i) * 512 + lane * 8, &gxL[cur ^ 1][(wid * 3 + i) * 512]);
      }
    }

    // ---------- phase 1: z,r ----------
    const int jb1 = wid * 64;                        // global col in [0,512)
    f32x4 acc[4];
    #pragma unroll
    for (int n = 0; n < 4; ++n) acc[n] = (f32x4){0.f, 0.f, 0.f, 0.f};
    #pragma unroll
    for (int kk = 0; kk < 8; ++kk) {
      bf16x8 af = *(const bf16x8*)&hA[l15][kk * 32 + lg * 8];
      #pragma unroll
      for (int n = 0; n < 4; ++n)
        acc[n] = __builtin_amdgcn_mfma_f32_16x16x32_bf16(af, w1[n][kk], acc[n], 0, 0, 0);
    }
    if (wid < 4) {         // z gate
      #pragma unroll
      for (int n = 0; n < 4; ++n) {
        const int col = jb1 + n * 16 + l15;
        uint2 gv = *(const uint2*)&gxL[cur][col * 16 + lg * 4];
        #pragma unroll
        for (int r = 0; r < 4; ++r) {
          float pre = acc[n][r] + bf2f(((const unsigned short*)&gv)[r]);
          zt_s[lg * 4 + r][col] = sigmoid_f(pre);
        }
      }
    } else {               // r gate -> r*h as bf16 A-frags
      #pragma unroll
      for (int n = 0; n < 4; ++n) {
        const int col = jb1 + n * 16 + l15;          // 256..511
        const int hc  = col - 256;
        uint2 gv = *(const uint2*)&gxL[cur][col * 16 + lg * 4];
        #pragma unroll
        for (int r = 0; r < 4; ++r) {
          const int row = lg * 4 + r;
          float pre = acc[n][r] + bf2f(((const unsigned short*)&gv)[r]);
          float rv  = sigmoid_f(pre);
          rhA[row][hc] = f2bf(rv * h_s[row][hc]);
        }
      }
    }
    __syncthreads();

    // ---------- phase 2: cand + h update ----------
    f32x4 acc2[2];
    #pragma unroll
    for (int n = 0; n < 2; ++n) acc2[n] = (f32x4){0.f, 0.f, 0.f, 0.f};
    #pragma unroll
    for (int kk = 0; kk < 8; ++kk) {
      bf16x8 af = *(const bf16x8*)&rhA[l15][kk * 32 + lg * 8];
      #pragma unroll
      for (int n = 0; n < 2; ++n)
        acc2[n] = __builtin_amdgcn_mfma_f32_16x16x32_bf16(af, w2[n][kk], acc2[n], 0, 0, 0);
    }
    #pragma unroll
    for (int n = 0; n < 2; ++n) {
      const int col = wid * 32 + n * 16 + l15;
      uint2 gv = *(const uint2*)&gxL[cur][(512 + col) * 16 + lg * 4];
      #pragma unroll
      for (int r = 0; r < 4; ++r) {
        const int row = lg * 4 + r;
        float pre = acc2[n][r] + bf2f(((const unsigned short*)&gv)[r]);
        float th  = tanh_f(pre);
        float zv  = zt_s[row][col];
        float hp  = h_s[row][col];
        float ht  = (1.f - zv) * hp + zv * th;
        out[(size_t)t * 65536 + (size_t)(brow0 + row) * 256 + col] = ht;
        if (t == 511)
          out[(size_t)33554432 + (size_t)(brow0 + row) * 256 + col] = ht;
        h_s[row][col] = ht;
        hA[row][col]  = f2bf(ht);
      }
    }
    __syncthreads();
    cur ^= 1;
  }
}

extern "C" void kernel_launch(void* const* d_in, const int* in_sizes, int n_in,
                              void* d_out, int out_size, void* d_ws, size_t ws_size,
                              hipStream_t stream) {
  const float* x  = (const float*)d_in[0];
  const float* h0 = (const float*)d_in[1];
  const float* Wz = (const float*)d_in[2];
  const float* bz = (const float*)d_in[3];
  const float* Wr = (const float*)d_in[4];
  const float* br = (const float*)d_in[5];
  const float* Wc = (const float*)d_in[6];
  const float* bc = (const float*)d_in[7];
  float* out = (float*)d_out;
  unsigned short* gxbuf = (unsigned short*)d_ws;   // 768*131072*2 = 201.3 MB

  dim3 gridA(2048, 12);
  gru_gx_kernel<<<gridA, 256, 0, stream>>>(x, Wz, Wr, Wc, bz, br, bc, gxbuf);
  gru_rec_kernel<<<16, 512, 0, stream>>>(gxbuf, h0, Wz, Wr, Wc, out);
}

// Round 4
// 1631.033 us; speedup vs baseline: 1.1582x; 1.1079x over previous
//
#include <hip/hip_runtime.h>

// GRU: T=512, B=256, I=H=256, fp32 in/out.
// Stage A (parallel GEMM): Gx = x @ Wx_cat^T + b, bf16 in d_ws.
//   Tile per (t, bgroup of 16 batch rows): [16 rows][768 cols] bf16,
//   row-swizzled: byte_in_row = col*2 ^ ((row&7)<<4)  (16B-granule XOR).
//   base = ((t*16 + bg) * 12288) shorts; tile = 24KB contiguous.
// Stage B (recurrent): 16 WGs x 512 thr; 16 batch rows/WG; weights in
//   registers as MFMA fragments for all 512 steps. MFMA operands SWAPPED
//   (D = W*h^T): output is [gate_col][batch] so each lane owns 4 consecutive
//   cols of one batch row -> fully vectorized epilogue (float4 LDS, cvt_pk
//   bf16 pairs, float4 global stores). gx folded into accumulator init.

typedef float f32x4 __attribute__((ext_vector_type(4)));
typedef short bf16x8 __attribute__((ext_vector_type(8)));

__device__ __forceinline__ unsigned short f2bf(float f) {
  union { float f; unsigned int u; } v; v.f = f;
  unsigned int u = v.u + 0x7fffu + ((v.u >> 16) & 1u);   // RNE
  return (unsigned short)(u >> 16);
}
__device__ __forceinline__ float u2f(unsigned int u) {
  union { unsigned int u; float f; } v; v.u = u; return v.f;
}
__device__ __forceinline__ unsigned int cvt_pk_bf16(float lo, float hi) {
  unsigned int r;
  asm("v_cvt_pk_bf16_f32 %0, %1, %2" : "=v"(r) : "v"(lo), "v"(hi));
  return r;
}
__device__ __forceinline__ float sigmoid_f(float x) {
  return __builtin_amdgcn_rcpf(1.f + __expf(-x));
}
__device__ __forceinline__ float tanh_f(float x) {
  float e = __expf(2.f * x);
  return 1.f - 2.f * __builtin_amdgcn_rcpf(e + 1.f);
}
__device__ __forceinline__ void gld_lds16(const unsigned short* g, unsigned short* l) {
  __builtin_amdgcn_global_load_lds(
      (const __attribute__((address_space(1))) unsigned int*)g,
      (__attribute__((address_space(3))) unsigned int*)l, 16, 0, 0);
}

// ---------------- Stage A ----------------
// grid (2048, 12), block 256 (4 waves). Tile 64M x 64N, K=256 in 4 chunks.
__global__ __launch_bounds__(256) void gru_gx_kernel(
    const float* __restrict__ x,
    const float* __restrict__ Wz, const float* __restrict__ Wr, const float* __restrict__ Wc,
    const float* __restrict__ bz, const float* __restrict__ br, const float* __restrict__ bc,
    unsigned short* __restrict__ gx)
{
  __shared__ __align__(16) unsigned short As[64][72];  // [m][k] bf16, +8 pad
  __shared__ __align__(16) unsigned short Bs[64][72];  // [j][k] bf16

  const int tid  = threadIdx.x;
  const int lane = tid & 63;
  const int wid  = tid >> 6;       // 0..3
  const int l15  = lane & 15;
  const int lg   = lane >> 4;      // 0..3
  const int m0   = blockIdx.x * 64;      // m = t*256 + b
  const int by   = blockIdx.y;           // 0..11
  const int gate = by >> 2;
  const int jb   = (by & 3) * 64;
  const float* W    = (gate == 0) ? Wz : ((gate == 1) ? Wr : Wc);
  const float* bias = (gate == 0) ? bz : ((gate == 1) ? br : bc);

  f32x4 acc[4];
  #pragma unroll
  for (int n = 0; n < 4; ++n) acc[n] = (f32x4){0.f, 0.f, 0.f, 0.f};

  for (int k0 = 0; k0 < 256; k0 += 64) {
    #pragma unroll
    for (int i = 0; i < 4; ++i) {
      int idx = tid + i * 256;              // 0..1023
      int row = idx >> 4;                   // 0..63
      int kq  = (idx & 15) << 2;            // 0..60 step 4
      float4 va = *(const float4*)(x + (size_t)(m0 + row) * 256 + k0 + kq);
      ushort4 ua; ua.x = f2bf(va.x); ua.y = f2bf(va.y); ua.z = f2bf(va.z); ua.w = f2bf(va.w);
      *(ushort4*)&As[row][kq] = ua;
      float4 vb = *(const float4*)(W + (size_t)(jb + row) * 512 + 256 + k0 + kq);
      ushort4 ub; ub.x = f2bf(vb.x); ub.y = f2bf(vb.y); ub.z = f2bf(vb.z); ub.w = f2bf(vb.w);
      *(ushort4*)&Bs[row][kq] = ub;
    }
    __syncthreads();
    #pragma unroll
    for (int ks = 0; ks < 64; ks += 32) {
      bf16x8 af = *(const bf16x8*)&As[wid * 16 + l15][ks + lg * 8];
      #pragma unroll
      for (int n = 0; n < 4; ++n) {
        bf16x8 bf = *(const bf16x8*)&Bs[n * 16 + l15][ks + lg * 8];
        acc[n] = __builtin_amdgcn_mfma_f32_16x16x32_bf16(af, bf, acc[n], 0, 0, 0);
      }
    }
    __syncthreads();
  }

  // bias + bf16; stage to LDS as Ts[m 64][j 64] (reuse As, row stride 72)
  #pragma unroll
  for (int n = 0; n < 4; ++n) {
    float bv = bias[jb + n * 16 + l15];
    #pragma unroll
    for (int r = 0; r < 4; ++r) {
      As[wid * 16 + lg * 4 + r][n * 16 + l15] = f2bf(acc[n][r] + bv);
    }
  }
  __syncthreads();

  const int tt    = m0 >> 8;       // t (tile spans a single t since 64 | 256)
  const int b0    = m0 & 255;      // batch base, 64-aligned
  const int jbase = by * 64;       // global output col
  #pragma unroll
  for (int i = 0; i < 2; ++i) {
    int idx  = tid + i * 256;      // 0..511
    int row  = idx >> 3;           // 0..63 (batch row within tile)
    int c8   = (idx & 7) * 8;      // col-8-group
    int b    = b0 + row;
    int bg   = b >> 4;
    int trow = b & 15;
    unsigned bir = (unsigned)((jbase + c8) * 2) ^ (unsigned)((trow & 7) << 4);
    char* dst = (char*)gx + ((size_t)tt * 16 + bg) * 24576 + (size_t)trow * 1536 + bir;
    *(uint4*)dst = *(const uint4*)&As[row][c8];
  }
}

// ---------------- Stage B ----------------
// grid 16, block 512 (8 waves). WG wg owns batch rows [16wg, 16wg+16).
// Phase 1: waves 0-3 -> z cols, waves 4-7 -> r cols. Phase 2: all -> cand.
__global__ __launch_bounds__(512, 1) void gru_rec_kernel(
    const unsigned short* __restrict__ gx,
    const float* __restrict__ h0,
    const float* __restrict__ Wz, const float* __restrict__ Wr, const float* __restrict__ Wc,
    float* __restrict__ out)
{
  __shared__ __align__(16) float h_s[16][260];           // [batch][col] f32
  __shared__ __align__(16) float zt_s[16][260];          // [batch][col] f32
  __shared__ __align__(16) unsigned short hA[16][264];   // [batch][k] bf16
  __shared__ __align__(16) unsigned short rhA[16][264];  // [batch][k] bf16
  __shared__ __align__(16) unsigned short gxL[2][12288]; // 2 x 24KB swizzled tiles

  const int tid   = threadIdx.x;
  const int lane  = tid & 63;
  const int wid   = tid >> 6;       // 0..7
  const int l15   = lane & 15;
  const int lg    = lane >> 4;      // 0..3
  const int wg    = blockIdx.x;
  const int brow0 = wg * 16;

  // ---- persistent weights: bf16 MFMA fragments (used as A operand) ----
  bf16x8 w1[4][8];   // phase-1: 64 cols (z or r), K=256
  {
    const float* W  = (wid < 4) ? Wz : Wr;
    const int    cb = (wid & 3) * 64;
    #pragma unroll
    for (int n = 0; n < 4; ++n) {
      const int j = cb + n * 16 + l15;
      #pragma unroll
      for (int kk = 0; kk < 8; ++kk) {
        const int k = kk * 32 + lg * 8;
        const float* p = W + (size_t)j * 512 + k;      // h-part: cols [0,256)
        float4 a = *(const float4*)p;
        float4 b = *(const float4*)(p + 4);
        bf16x8 f;
        f[0] = (short)f2bf(a.x); f[1] = (short)f2bf(a.y);
        f[2] = (short)f2bf(a.z); f[3] = (short)f2bf(a.w);
        f[4] = (short)f2bf(b.x); f[5] = (short)f2bf(b.y);
        f[6] = (short)f2bf(b.z); f[7] = (short)f2bf(b.w);
        w1[n][kk] = f;
      }
    }
  }
  bf16x8 w2[2][8];   // phase-2: 32 cand cols, K=256
  {
    const int cb = wid * 32;
    #pragma unroll
    for (int n = 0; n < 2; ++n) {
      const int j = cb + n * 16 + l15;
      #pragma unroll
      for (int kk = 0; kk < 8; ++kk) {
        const int k = kk * 32 + lg * 8;
        const float* p = Wc + (size_t)j * 512 + k;
        float4 a = *(const float4*)p;
        float4 b = *(const float4*)(p + 4);
        bf16x8 f;
        f[0] = (short)f2bf(a.x); f[1] = (short)f2bf(a.y);
        f[2] = (short)f2bf(a.z); f[3] = (short)f2bf(a.w);
        f[4] = (short)f2bf(b.x); f[5] = (short)f2bf(b.y);
        f[6] = (short)f2bf(b.z); f[7] = (short)f2bf(b.w);
        w2[n][kk] = f;
      }
    }
  }

  // ---- init h + prefetch step 0 ----
  for (int idx = tid; idx < 16 * 256; idx += 512) {
    int r = idx >> 8, c = idx & 255;
    float v = h0[(size_t)(brow0 + r) * 256 + c];
    h_s[r][c] = v;
    hA[r][c]  = f2bf(v);
  }
  {
    const unsigned short* src = gx + (size_t)wg * 12288;
    #pragma unroll
    for (int i = 0; i < 3; ++i) {
      gld_lds16(src + (wid * 3 + i) * 512 + lane * 8, &gxL[0][(wid * 3 + i) * 512]);
    }
  }
  __syncthreads();   // drains vmcnt -> gxL[0] ready; h_s/hA visible

  int cur = 0;
  for (int t = 0; t < 512; ++t) {
    // ---- prefetch step t+1 into the other buffer ----
    {
      const int tn = (t < 511) ? (t + 1) : 511;
      const unsigned short* src = gx + ((size_t)tn * 16 + wg) * 12288;
      #pragma unroll
      for (int i = 0; i < 3; ++i) {
        gld_lds16(src + (wid * 3 + i) * 512 + lane * 8, &gxL[cur ^ 1][(wid * 3 + i) * 512]);
      }
    }

    const char* gbase = (const char*)&gxL[cur][0];
    const unsigned rowoff = (unsigned)(l15 * 1536);
    const unsigned rxor   = (unsigned)((l15 & 7) << 4);

    // ---------- phase 1: z,r ----------
    // acc init from gx (bias already folded in by stage A)
    const int cb1 = wid * 64;          // gx col base (z: 0..255, r: 256..511)
    f32x4 acc[4];
    #pragma unroll
    for (int n = 0; n < 4; ++n) {
      const int c0 = cb1 + n * 16 + lg * 4;
      uint2 gv = *(const uint2*)(gbase + rowoff + (((unsigned)(c0 * 2)) ^ rxor));
      acc[n][0] = u2f(gv.x << 16); acc[n][1] = u2f(gv.x & 0xffff0000u);
      acc[n][2] = u2f(gv.y << 16); acc[n][3] = u2f(gv.y & 0xffff0000u);
    }
    #pragma unroll
    for (int kk = 0; kk < 8; ++kk) {
      bf16x8 hf = *(const bf16x8*)&hA[l15][kk * 32 + lg * 8];
      #pragma unroll
      for (int n = 0; n < 4; ++n)    // SWAPPED: weights as A, h^T as B
        acc[n] = __builtin_amdgcn_mfma_f32_16x16x32_bf16(w1[n][kk], hf, acc[n], 0, 0, 0);
    }
    if (wid < 4) {         // z gate: zt_s[batch=l15][4 consecutive cols]
      #pragma unroll
      for (int n = 0; n < 4; ++n) {
        const int c0 = cb1 + n * 16 + lg * 4;
        f32x4 zv;
        #pragma unroll
        for (int r = 0; r < 4; ++r) zv[r] = sigmoid_f(acc[n][r]);
        *(f32x4*)&zt_s[l15][c0] = zv;
      }
    } else {               // r gate -> rh = r*h, bf16 pairs
      #pragma unroll
      for (int n = 0; n < 4; ++n) {
        const int c0h = (cb1 - 256) + n * 16 + lg * 4;   // hidden col
        f32x4 hv = *(const f32x4*)&h_s[l15][c0h];
        float rh0 = sigmoid_f(acc[n][0]) * hv[0];
        float rh1 = sigmoid_f(acc[n][1]) * hv[1];
        float rh2 = sigmoid_f(acc[n][2]) * hv[2];
        float rh3 = sigmoid_f(acc[n][3]) * hv[3];
        uint2 pk; pk.x = cvt_pk_bf16(rh0, rh1); pk.y = cvt_pk_bf16(rh2, rh3);
        *(uint2*)&rhA[l15][c0h] = pk;
      }
    }
    __syncthreads();

    // ---------- phase 2: cand + h update ----------
    f32x4 acc2[2];
    #pragma unroll
    for (int n = 0; n < 2; ++n) {
      const int c0 = 512 + wid * 32 + n * 16 + lg * 4;   // gx cand col
      uint2 gv = *(const uint2*)(gbase + rowoff + (((unsigned)(c0 * 2)) ^ rxor));
      acc2[n][0] = u2f(gv.x << 16); acc2[n][1] = u2f(gv.x & 0xffff0000u);
      acc2[n][2] = u2f(gv.y << 16); acc2[n][3] = u2f(gv.y & 0xffff0000u);
    }
    #pragma unroll
    for (int kk = 0; kk < 8; ++kk) {
      bf16x8 rf = *(const bf16x8*)&rhA[l15][kk * 32 + lg * 8];
      #pragma unroll
      for (int n = 0; n < 2; ++n)
        acc2[n] = __builtin_amdgcn_mfma_f32_16x16x32_bf16(w2[n][kk], rf, acc2[n], 0, 0, 0);
    }
    #pragma unroll
    for (int n = 0; n < 2; ++n) {
      const int j0 = wid * 32 + n * 16 + lg * 4;
      f32x4 zv = *(const f32x4*)&zt_s[l15][j0];
      f32x4 hp = *(const f32x4*)&h_s[l15][j0];
      f32x4 ht;
      #pragma unroll
      for (int r = 0; r < 4; ++r) {
        float th = tanh_f(acc2[n][r]);
        ht[r] = hp[r] + zv[r] * (th - hp[r]);
      }
      *(f32x4*)(out + (size_t)t * 65536 + (size_t)(brow0 + l15) * 256 + j0) = ht;
      if (t == 511)
        *(f32x4*)(out + (size_t)33554432 + (size_t)(brow0 + l15) * 256 + j0) = ht;
      *(f32x4*)&h_s[l15][j0] = ht;
      uint2 pk; pk.x = cvt_pk_bf16(ht[0], ht[1]); pk.y = cvt_pk_bf16(ht[2], ht[3]);
      *(uint2*)&hA[l15][j0] = pk;
    }
    __syncthreads();
    cur ^= 1;
  }
}

extern "C" void kernel_launch(void* const* d_in, const int* in_sizes, int n_in,
                              void* d_out, int out_size, void* d_ws, size_t ws_size,
                              hipStream_t stream) {
  const float* x  = (const float*)d_in[0];
  const float* h0 = (const float*)d_in[1];
  const float* Wz = (const float*)d_in[2];
  const float* bz = (const float*)d_in[3];
  const float* Wr = (const float*)d_in[4];
  const float* br = (const float*)d_in[5];
  const float* Wc = (const float*)d_in[6];
  const float* bc = (const float*)d_in[7];
  float* out = (float*)d_out;
  unsigned short* gxbuf = (unsigned short*)d_ws;   // 768*131072*2 = 201.3 MB

  dim3 gridA(2048, 12);
  gru_gx_kernel<<<gridA, 256, 0, stream>>>(x, Wz, Wr, Wc, bz, br, bc, gxbuf);
  gru_rec_kernel<<<16, 512, 0, stream>>>(gxbuf, h0, Wz, Wr, Wc, out);
}